// Round 2
// baseline (11572.715 us; speedup 1.0000x reference)
//
#include <hip/hip_runtime.h>

// Problem constants (b=8, n=1024, m=1024, d=256, RHO=1, LAMBDA=0.1, 50 iters)
// Algorithm: ADMM box-QP via Woodbury on A = I + 2 Vs Vs^T  (Vs = V / 1024).
//   state e (f64):  z = clip(e), s = 2z - e
//   w  = W1 @ s - Pvp            (fp32, K=1024)   W1 = M Vs^T, Pvp = M Vs^T P
//   e' = clip(e) - P - (2/1024) * (V @ w)   (fp32 K=256 + f64 elementwise)
//   M  = (I + 2G)^-1, G = Vs^T Vs  — Newton-Schulz x3 in f64
// The n=1024 QPs per batch are COLUMN-INDEPENDENT -> one persistent block owns
// 16 columns for all 50 iterations (s,w in LDS; e in VGPRs). Math is kept
// bitwise-identical to the round-1 kernel (same ascending-k fp32 FMA chains).

__device__ __forceinline__ double clip01(double v) { return fmin(fmax(v, 0.0), 1.0); }

// ---------------- NT GEMM, f64 accumulate: C = (TC)(alpha * A@B^T + c0) ----------
template <typename TA, typename TC>
__global__ __launch_bounds__(256) void k_gemm_nt(
    const TA* __restrict__ Ag, const float* __restrict__ Bg, TC* __restrict__ Cg,
    int M, int N, int K, long sA, long sB, long sC, double alpha, double c0)
{
  const TA* A = Ag + (long)blockIdx.z * sA;
  const float* B = Bg + (long)blockIdx.z * sB;
  TC* C = Cg + (long)blockIdx.z * sC;
  const int m0 = blockIdx.x * 64, n0 = blockIdx.y * 64;
  const int tid = threadIdx.x;
  __shared__ double As[32][68];
  __shared__ double Bs[32][68];
  const int tx = tid & 15, ty = tid >> 4;
  const int r = tid >> 2, kq = (tid & 3) * 8;
  double acc[4][4] = {};
  for (int k0 = 0; k0 < K; k0 += 32) {
    if constexpr (sizeof(TA) == 4) {
      const float4* ap = reinterpret_cast<const float4*>(A + (size_t)(m0 + r) * K + k0 + kq);
      float4 a0 = ap[0], a1 = ap[1];
      As[kq+0][r] = a0.x; As[kq+1][r] = a0.y; As[kq+2][r] = a0.z; As[kq+3][r] = a0.w;
      As[kq+4][r] = a1.x; As[kq+5][r] = a1.y; As[kq+6][r] = a1.z; As[kq+7][r] = a1.w;
    } else {
      const double2* ap = reinterpret_cast<const double2*>(A + (size_t)(m0 + r) * K + k0 + kq);
      double2 a0 = ap[0], a1 = ap[1], a2 = ap[2], a3 = ap[3];
      As[kq+0][r] = a0.x; As[kq+1][r] = a0.y; As[kq+2][r] = a1.x; As[kq+3][r] = a1.y;
      As[kq+4][r] = a2.x; As[kq+5][r] = a2.y; As[kq+6][r] = a3.x; As[kq+7][r] = a3.y;
    }
    {
      const float4* bp = reinterpret_cast<const float4*>(B + (size_t)(n0 + r) * K + k0 + kq);
      float4 b0 = bp[0], b1 = bp[1];
      Bs[kq+0][r] = b0.x; Bs[kq+1][r] = b0.y; Bs[kq+2][r] = b0.z; Bs[kq+3][r] = b0.w;
      Bs[kq+4][r] = b1.x; Bs[kq+5][r] = b1.y; Bs[kq+6][r] = b1.z; Bs[kq+7][r] = b1.w;
    }
    __syncthreads();
#pragma unroll
    for (int kk = 0; kk < 32; ++kk) {
      double a_[4], b_[4];
#pragma unroll
      for (int i = 0; i < 4; ++i) a_[i] = As[kk][ty * 4 + i];
#pragma unroll
      for (int j = 0; j < 4; ++j) b_[j] = Bs[kk][tx * 4 + j];
#pragma unroll
      for (int i = 0; i < 4; ++i)
#pragma unroll
        for (int j = 0; j < 4; ++j) acc[i][j] = fma(a_[i], b_[j], acc[i][j]);
    }
    __syncthreads();
  }
#pragma unroll
  for (int i = 0; i < 4; ++i) {
    int row = m0 + ty * 4 + i;
#pragma unroll
    for (int j = 0; j < 4; ++j)
      C[(size_t)row * N + n0 + tx * 4 + j] = (TC)(alpha * acc[i][j] + c0);
  }
}

// ---------------- TN GEMM, f64 accumulate: C[MxN] = scale * A^T @ B -------------
template <typename TB>
__global__ __launch_bounds__(256) void k_gemm_tn(
    const float* __restrict__ Ag, const TB* __restrict__ Bg, double* __restrict__ Cg,
    int M, int N, int K, long sA, long sB, long sC, double scale)
{
  const float* A = Ag + (long)blockIdx.z * sA;
  const TB* B = Bg + (long)blockIdx.z * sB;
  double* C = Cg + (long)blockIdx.z * sC;
  const int m0 = blockIdx.x * 64, n0 = blockIdx.y * 64;
  const int tid = threadIdx.x;
  __shared__ float As[16][68];
  __shared__ double Bs[16][68];
  const int tx = tid & 15, ty = tid >> 4;
  const int kk = tid >> 4, c4 = (tid & 15) * 4;
  double acc[4][4] = {};
  for (int k0 = 0; k0 < K; k0 += 16) {
    float4 av = *reinterpret_cast<const float4*>(A + (size_t)(k0 + kk) * M + m0 + c4);
    *reinterpret_cast<float4*>(&As[kk][c4]) = av;
    if constexpr (sizeof(TB) == 4) {
      float4 bv = *reinterpret_cast<const float4*>(B + (size_t)(k0 + kk) * N + n0 + c4);
      Bs[kk][c4 + 0] = bv.x; Bs[kk][c4 + 1] = bv.y; Bs[kk][c4 + 2] = bv.z; Bs[kk][c4 + 3] = bv.w;
    } else {
      const double2* bp = reinterpret_cast<const double2*>(B + (size_t)(k0 + kk) * N + n0 + c4);
      double2 b0 = bp[0], b1 = bp[1];
      *reinterpret_cast<double2*>(&Bs[kk][c4]) = b0;
      *reinterpret_cast<double2*>(&Bs[kk][c4 + 2]) = b1;
    }
    __syncthreads();
#pragma unroll
    for (int k = 0; k < 16; ++k) {
      double a_[4], b_[4];
#pragma unroll
      for (int i = 0; i < 4; ++i) a_[i] = (double)As[k][ty * 4 + i];
#pragma unroll
      for (int j = 0; j < 4; ++j) b_[j] = Bs[k][tx * 4 + j];
#pragma unroll
      for (int i = 0; i < 4; ++i)
#pragma unroll
        for (int j = 0; j < 4; ++j) acc[i][j] = fma(a_[i], b_[j], acc[i][j]);
    }
    __syncthreads();
  }
#pragma unroll
  for (int i = 0; i < 4; ++i) {
    int row = m0 + ty * 4 + i;
#pragma unroll
    for (int j = 0; j < 4; ++j)
      C[(size_t)row * N + n0 + tx * 4 + j] = scale * acc[i][j];
  }
}

// ---------------- Ad = I + 2G, X0 = I - 2G --------------------------------------
__global__ __launch_bounds__(256) void k_adx0(const double* __restrict__ G,
                                              double* __restrict__ Ad, double* __restrict__ X)
{
  size_t idx = (size_t)blockIdx.x * 256 + threadIdx.x;
  double g = G[idx];
  int ij = (int)(idx & 65535);
  double dg = ((ij >> 8) == (ij & 255)) ? 1.0 : 0.0;
  Ad[idx] = dg + 2.0 * g;
  X[idx] = dg - 2.0 * g;
}

// ---------------- small f64 NN GEMM: C = alpha*A@B + beta*Xin -------------------
template <bool F32OUT>
__global__ __launch_bounds__(256) void k_smallmm(
    const double* __restrict__ Ag, const double* __restrict__ Bg,
    const double* __restrict__ Xg, void* __restrict__ Cg,
    int N, long sB, long sC, double alpha, double beta)
{
  const double* A = Ag + (long)blockIdx.z * 65536;
  const double* B = Bg + (long)blockIdx.z * sB;
  const double* Xp = Xg ? (Xg + (long)blockIdx.z * sB) : (const double*)nullptr;
  const int m0 = blockIdx.x * 64, n0 = blockIdx.y * 64;
  const int tid = threadIdx.x;
  __shared__ double As[16][68];
  __shared__ double Bs[16][68];
  const int tx = tid & 15, ty = tid >> 4;
  const int ra = tid >> 2, kqa = (tid & 3) * 4;
  const int kb = tid >> 4, cb = (tid & 15) * 4;
  double acc[4][4] = {};
  for (int k0 = 0; k0 < 256; k0 += 16) {
    const double2* ap = reinterpret_cast<const double2*>(A + (size_t)(m0 + ra) * 256 + k0 + kqa);
    double2 a0 = ap[0], a1 = ap[1];
    As[kqa + 0][ra] = a0.x; As[kqa + 1][ra] = a0.y; As[kqa + 2][ra] = a1.x; As[kqa + 3][ra] = a1.y;
    const double2* bp = reinterpret_cast<const double2*>(B + (size_t)(k0 + kb) * N + n0 + cb);
    double2 b0 = bp[0], b1 = bp[1];
    *reinterpret_cast<double2*>(&Bs[kb][cb]) = b0;
    *reinterpret_cast<double2*>(&Bs[kb][cb + 2]) = b1;
    __syncthreads();
#pragma unroll
    for (int k = 0; k < 16; ++k) {
      double a_[4], b_[4];
#pragma unroll
      for (int i = 0; i < 4; ++i) a_[i] = As[k][ty * 4 + i];
#pragma unroll
      for (int j = 0; j < 4; ++j) b_[j] = Bs[k][tx * 4 + j];
#pragma unroll
      for (int i = 0; i < 4; ++i)
#pragma unroll
        for (int j = 0; j < 4; ++j) acc[i][j] = fma(a_[i], b_[j], acc[i][j]);
    }
    __syncthreads();
  }
#pragma unroll
  for (int i = 0; i < 4; ++i) {
    int row = m0 + ty * 4 + i;
#pragma unroll
    for (int j = 0; j < 4; ++j) {
      int col = n0 + tx * 4 + j;
      double v = alpha * acc[i][j];
      if (beta != 0.0) v = fma(beta, Xp[(size_t)row * N + col], v);
      if constexpr (F32OUT)
        ((float*)Cg)[(long)blockIdx.z * sC + (size_t)row * N + col] = (float)v;
      else
        ((double*)Cg)[(long)blockIdx.z * sC + (size_t)row * N + col] = v;
    }
  }
}

// ---------------- paired transpose: out[(c/2)][r][c&1] = in[r][c] ---------------
// in: (R,C) f32 row-major -> out laid out so that lane-consecutive float2 loads
// give two consecutive-k elements of row r. Pure data movement (bitwise).
__global__ __launch_bounds__(256) void k_transpose_pair(
    const float* __restrict__ in, float* __restrict__ out, int R, int C)
{
  __shared__ float t[32][33];
  const float* ip = in + (size_t)blockIdx.z * R * C;
  float* op = out + (size_t)blockIdx.z * R * C;
  const int r0 = blockIdx.x * 32, c0 = blockIdx.y * 32;
  const int tx = threadIdx.x & 31, ty = threadIdx.x >> 5;
#pragma unroll
  for (int i = 0; i < 4; ++i)
    t[ty + i * 8][tx] = ip[(size_t)(r0 + ty + i * 8) * C + c0 + tx];
  __syncthreads();
#pragma unroll
  for (int i = 0; i < 4; ++i) {
    int c = c0 + ty + i * 8;
    int r = r0 + tx;
    op[((size_t)(c >> 1) * R + r) * 2 + (c & 1)] = t[tx][ty + i * 8];
  }
}

// ---------------- persistent ADMM kernel ----------------------------------------
// Block owns batch b = bid&7 (XCD-pinned), columns j0..j0+15. 512 threads.
// s (1024x16 f32) and w (256x16 f32) in LDS; e rows {tid, tid+512} in VGPRs.
__global__ __launch_bounds__(512, 4) void k_persist(
    const float* __restrict__ W1Tg, const float* __restrict__ VTg,
    const float* __restrict__ PVPg, const double* __restrict__ Pg,
    double* __restrict__ Eg)
{
  const int bid = blockIdx.x;
  const int b = bid & 7;
  const int j0 = (bid >> 3) << 4;
  const float* W1Tp = W1Tg + (size_t)b * 262144;   // paired [512][256][2]
  const float* VTp  = VTg  + (size_t)b * 262144;   // paired [128][1024][2]
  const float* PVPg2 = PVPg + (size_t)b * 262144;  // [256][1024]
  const double* P  = Pg + (size_t)b * 1048576 + j0;
  double* E        = Eg + (size_t)b * 1048576 + j0;
  const int tid = threadIdx.x;          // 0..511
  const int wrow = tid & 255;           // phase-1 output row of w
  const int whalf = (tid >> 8) << 3;    // 0 or 8: phase-1 column half

  __shared__ float s_ld[1024][16];      // 64 KB
  __shared__ float w_ld[256][16];       // 16 KB

  double e0[16], e1[16];                // e rows tid and tid+512, 16 cols
#pragma unroll
  for (int c = 0; c < 16; ++c) { e0[c] = 0.0; e1[c] = 0.0; }

  {
    const float4 z4 = {0.f, 0.f, 0.f, 0.f};
#pragma unroll
    for (int q = 0; q < 4; ++q) {
      *reinterpret_cast<float4*>(&s_ld[tid][q * 4]) = z4;
      *reinterpret_cast<float4*>(&s_ld[tid + 512][q * 4]) = z4;
    }
  }
  __syncthreads();

  const double cg = 2.0 / 1024.0;
  const float* w1p = W1Tp + wrow * 2;
  const float* vpa = VTp + tid * 2;
  const float* vpb = VTp + (tid + 512) * 2;
  const float* pvp = PVPg2 + (size_t)wrow * 1024 + j0 + whalf;
  const double* pr0 = P + (size_t)tid * 1024;
  const double* pr1 = P + (size_t)(tid + 512) * 1024;

  for (int it = 0; it < 50; ++it) {
    // ---------- phase 1: w[wrow][whalf..+7] = sum_k W1[wrow,k]*s[k,c] ----------
    float wa[8];
#pragma unroll
    for (int c = 0; c < 8; ++c) wa[c] = 0.0f;
#pragma unroll 4
    for (int k2 = 0; k2 < 512; ++k2) {
      float2 a2 = *reinterpret_cast<const float2*>(w1p + (size_t)k2 * 512);
      float sA[8], sB[8];
      *reinterpret_cast<float4*>(&sA[0]) = *reinterpret_cast<const float4*>(&s_ld[2 * k2][whalf]);
      *reinterpret_cast<float4*>(&sA[4]) = *reinterpret_cast<const float4*>(&s_ld[2 * k2][whalf + 4]);
#pragma unroll
      for (int c = 0; c < 8; ++c) wa[c] = fmaf(a2.x, sA[c], wa[c]);
      *reinterpret_cast<float4*>(&sB[0]) = *reinterpret_cast<const float4*>(&s_ld[2 * k2 + 1][whalf]);
      *reinterpret_cast<float4*>(&sB[4]) = *reinterpret_cast<const float4*>(&s_ld[2 * k2 + 1][whalf + 4]);
#pragma unroll
      for (int c = 0; c < 8; ++c) wa[c] = fmaf(a2.y, sB[c], wa[c]);
    }
    {
      float4 pv0 = *reinterpret_cast<const float4*>(pvp);
      float4 pv1 = *reinterpret_cast<const float4*>(pvp + 4);
      float4 o0; o0.x = wa[0] - pv0.x; o0.y = wa[1] - pv0.y; o0.z = wa[2] - pv0.z; o0.w = wa[3] - pv0.w;
      float4 o1; o1.x = wa[4] - pv1.x; o1.y = wa[5] - pv1.y; o1.z = wa[6] - pv1.z; o1.w = wa[7] - pv1.w;
      *reinterpret_cast<float4*>(&w_ld[wrow][whalf]) = o0;
      *reinterpret_cast<float4*>(&w_ld[wrow][whalf + 4]) = o1;
    }
    __syncthreads();

    // ---------- phase 2 + elementwise, two 8-column halves ----------
#pragma unroll
    for (int half = 0; half < 2; ++half) {
      const int co = half * 8;
      float g0[8], g1[8];
#pragma unroll
      for (int c = 0; c < 8; ++c) { g0[c] = 0.0f; g1[c] = 0.0f; }
#pragma unroll 2
      for (int k2 = 0; k2 < 128; ++k2) {
        float2 va = *reinterpret_cast<const float2*>(vpa + (size_t)k2 * 2048);
        float2 vb = *reinterpret_cast<const float2*>(vpb + (size_t)k2 * 2048);
        {
          float wv[8];
          *reinterpret_cast<float4*>(&wv[0]) = *reinterpret_cast<const float4*>(&w_ld[2 * k2][co]);
          *reinterpret_cast<float4*>(&wv[4]) = *reinterpret_cast<const float4*>(&w_ld[2 * k2][co + 4]);
#pragma unroll
          for (int c = 0; c < 8; ++c) {
            g0[c] = fmaf(va.x, wv[c], g0[c]);
            g1[c] = fmaf(vb.x, wv[c], g1[c]);
          }
        }
        {
          float wv[8];
          *reinterpret_cast<float4*>(&wv[0]) = *reinterpret_cast<const float4*>(&w_ld[2 * k2 + 1][co]);
          *reinterpret_cast<float4*>(&wv[4]) = *reinterpret_cast<const float4*>(&w_ld[2 * k2 + 1][co + 4]);
#pragma unroll
          for (int c = 0; c < 8; ++c) {
            g0[c] = fmaf(va.y, wv[c], g0[c]);
            g1[c] = fmaf(vb.y, wv[c], g1[c]);
          }
        }
      }
      // elementwise: row tid (e0) then row tid+512 (e1), cols co..co+7
      {
        double2 pA = *reinterpret_cast<const double2*>(pr0 + co);
        double2 pB = *reinterpret_cast<const double2*>(pr0 + co + 2);
        double2 pC = *reinterpret_cast<const double2*>(pr0 + co + 4);
        double2 pD = *reinterpret_cast<const double2*>(pr0 + co + 6);
        double p_[8] = {pA.x, pA.y, pB.x, pB.y, pC.x, pC.y, pD.x, pD.y};
        float s_[8];
#pragma unroll
        for (int u = 0; u < 8; ++u) {
          double z = clip01(e0[co + u]);
          double en = z - p_[u] - cg * (double)g0[u];
          e0[co + u] = en;
          s_[u] = (float)(2.0 * clip01(en) - en);
        }
        float4 sv0; sv0.x = s_[0]; sv0.y = s_[1]; sv0.z = s_[2]; sv0.w = s_[3];
        float4 sv1; sv1.x = s_[4]; sv1.y = s_[5]; sv1.z = s_[6]; sv1.w = s_[7];
        *reinterpret_cast<float4*>(&s_ld[tid][co]) = sv0;
        *reinterpret_cast<float4*>(&s_ld[tid][co + 4]) = sv1;
      }
      {
        double2 pA = *reinterpret_cast<const double2*>(pr1 + co);
        double2 pB = *reinterpret_cast<const double2*>(pr1 + co + 2);
        double2 pC = *reinterpret_cast<const double2*>(pr1 + co + 4);
        double2 pD = *reinterpret_cast<const double2*>(pr1 + co + 6);
        double p_[8] = {pA.x, pA.y, pB.x, pB.y, pC.x, pC.y, pD.x, pD.y};
        float s_[8];
#pragma unroll
        for (int u = 0; u < 8; ++u) {
          double z = clip01(e1[co + u]);
          double en = z - p_[u] - cg * (double)g1[u];
          e1[co + u] = en;
          s_[u] = (float)(2.0 * clip01(en) - en);
        }
        float4 sv0; sv0.x = s_[0]; sv0.y = s_[1]; sv0.z = s_[2]; sv0.w = s_[3];
        float4 sv1; sv1.x = s_[4]; sv1.y = s_[5]; sv1.z = s_[6]; sv1.w = s_[7];
        *reinterpret_cast<float4*>(&s_ld[tid + 512][co]) = sv0;
        *reinterpret_cast<float4*>(&s_ld[tid + 512][co + 4]) = sv1;
      }
    }
    __syncthreads();
  }

  // final E store
#pragma unroll
  for (int q = 0; q < 8; ++q) {
    double2 v0; v0.x = e0[2 * q]; v0.y = e0[2 * q + 1];
    *reinterpret_cast<double2*>(E + (size_t)tid * 1024 + 2 * q) = v0;
  }
#pragma unroll
  for (int q = 0; q < 8; ++q) {
    double2 v1; v1.x = e1[2 * q]; v1.y = e1[2 * q + 1];
    *reinterpret_cast<double2*>(E + (size_t)(tid + 512) * 1024 + 2 * q) = v1;
  }
}

// ---------------- per-(b,n) count -> inverse scale ------------------------------
__global__ __launch_bounds__(256) void k_count(const double* __restrict__ Eg, float* __restrict__ inv)
{
  const int bz = blockIdx.y;
  const int j = blockIdx.x * 256 + threadIdx.x;
  const double* E = Eg + (size_t)bz * 1048576;
  int c = 0;
  for (int i = 0; i < 1024; ++i) c += (E[(size_t)i * 1024 + j] > 0.5) ? 1 : 0;
  inv[bz * 1024 + j] = (float)(1.0 / (((double)c) + 1e-10) / 1024.0);
}

// ---------------- output masked GEMM: out[j,dd] = inv[j] * sum_i mask(e) V[i,dd] --
__global__ __launch_bounds__(256) void k_out(
    const double* __restrict__ Eg, const float* __restrict__ Vg,
    const float* __restrict__ invg, float* __restrict__ Og)
{
  const double* E = Eg + (size_t)blockIdx.z * 1048576;
  const float* Vv = Vg + (size_t)blockIdx.z * 262144;
  const float* inv = invg + blockIdx.z * 1024;
  float* O = Og + (size_t)blockIdx.z * 262144;
  const int j0 = blockIdx.x * 64, d0 = blockIdx.y * 128;
  const int tid = threadIdx.x;
  __shared__ float As[32][68];
  __shared__ float Bs[32][132];
  const int tx = tid & 15, ty = tid >> 4;
  const int ka = tid >> 3, ja = (tid & 7) * 8;
  const int rb = tid >> 5, cb = (tid & 31) * 4;
  float acc[4][8] = {};
  for (int k0 = 0; k0 < 1024; k0 += 32) {
    {
      const double2* ep = reinterpret_cast<const double2*>(E + (size_t)(k0 + ka) * 1024 + j0 + ja);
      double2 e0 = ep[0], e1 = ep[1], e2 = ep[2], e3 = ep[3];
      As[ka][ja + 0] = (e0.x > 0.5) ? 1.0f : 0.0f;
      As[ka][ja + 1] = (e0.y > 0.5) ? 1.0f : 0.0f;
      As[ka][ja + 2] = (e1.x > 0.5) ? 1.0f : 0.0f;
      As[ka][ja + 3] = (e1.y > 0.5) ? 1.0f : 0.0f;
      As[ka][ja + 4] = (e2.x > 0.5) ? 1.0f : 0.0f;
      As[ka][ja + 5] = (e2.y > 0.5) ? 1.0f : 0.0f;
      As[ka][ja + 6] = (e3.x > 0.5) ? 1.0f : 0.0f;
      As[ka][ja + 7] = (e3.y > 0.5) ? 1.0f : 0.0f;
    }
#pragma unroll
    for (int p = 0; p < 4; ++p) {
      int krow = rb + p * 8;
      float4 bv = *reinterpret_cast<const float4*>(Vv + (size_t)(k0 + krow) * 256 + d0 + cb);
      *reinterpret_cast<float4*>(&Bs[krow][cb]) = bv;
    }
    __syncthreads();
#pragma unroll
    for (int kk = 0; kk < 32; ++kk) {
      float4 av = *reinterpret_cast<const float4*>(&As[kk][ty * 4]);
      float4 b0 = *reinterpret_cast<const float4*>(&Bs[kk][tx * 8]);
      float4 b1 = *reinterpret_cast<const float4*>(&Bs[kk][tx * 8 + 4]);
      float a_[4] = {av.x, av.y, av.z, av.w};
      float b_[8] = {b0.x, b0.y, b0.z, b0.w, b1.x, b1.y, b1.z, b1.w};
#pragma unroll
      for (int i = 0; i < 4; ++i)
#pragma unroll
        for (int j = 0; j < 8; ++j) acc[i][j] = fmaf(a_[i], b_[j], acc[i][j]);
    }
    __syncthreads();
  }
#pragma unroll
  for (int i = 0; i < 4; ++i) {
    int row = j0 + ty * 4 + i;
    float sc = inv[row];
    size_t base = (size_t)row * 256 + d0 + tx * 8;
    float4 o0 = {acc[i][0] * sc, acc[i][1] * sc, acc[i][2] * sc, acc[i][3] * sc};
    float4 o1 = {acc[i][4] * sc, acc[i][5] * sc, acc[i][6] * sc, acc[i][7] * sc};
    *reinterpret_cast<float4*>(O + base) = o0;
    *reinterpret_cast<float4*>(O + base + 4) = o1;
  }
}

extern "C" void kernel_launch(void* const* d_in, const int* in_sizes, int n_in,
                              void* d_out, int out_size, void* d_ws, size_t ws_size,
                              hipStream_t stream)
{
  const float* Q = (const float*)d_in[0];   // (8,1024,256)
  const float* V = (const float*)d_in[1];   // (8,1024,256)
  float* out = (float*)d_out;               // (8,1024,256)
  char* ws = (char*)d_ws;

  // workspace layout (bytes) — total ~193 MB
  const size_t OFF_E   = 0;                  // e final, f64 (8,1024,1024)
  const size_t OFF_P   = 67108864;           // P, f64 (8,1024,1024)
  const size_t SCR     = 134217728;          // scratch region
  const size_t OFF_G   = SCR;
  const size_t OFF_AD  = SCR + 4194304;
  const size_t OFF_X   = SCR + 8388608;
  const size_t OFF_Y   = SCR + 12582912;
  const size_t OFF_X2  = SCR + 16777216;     // final M
  const size_t OFF_PV64= SCR;                // f64 (8,256,1024) overlays G..Y
  const size_t OFF_W1T = SCR;                // fp32 paired W1^T (8MB) — after PV64 dead
  const size_t OFF_VT  = SCR + 8388608;      // fp32 paired V^T (8MB)
  const size_t OFF_W1  = 176160768;          // fp32 W1 (8,256,1024)
  const size_t OFF_PVP = 184549376;          // fp32 Pvp (8,256,1024)
  const size_t OFF_INV = 192937984;          // fp32 (8,1024)

  double* E    = (double*)(ws + OFF_E);
  double* P    = (double*)(ws + OFF_P);
  double* G    = (double*)(ws + OFF_G);
  double* Ad   = (double*)(ws + OFF_AD);
  double* X    = (double*)(ws + OFF_X);
  double* Y    = (double*)(ws + OFF_Y);
  double* X2   = (double*)(ws + OFF_X2);
  double* PV64 = (double*)(ws + OFF_PV64);
  float*  W1T  = (float*)(ws + OFF_W1T);
  float*  VT   = (float*)(ws + OFF_VT);
  float*  W1   = (float*)(ws + OFF_W1);
  float*  PVP  = (float*)(ws + OFF_PVP);
  float*  INV  = (float*)(ws + OFF_INV);

  (void)in_sizes; (void)n_in; (void)out_size; (void)ws_size;

  // P = (-2/1024) * V @ Q^T + 0.1/1024     (f64, K=256)
  k_gemm_nt<float, double><<<dim3(16, 16, 8), 256, 0, stream>>>(
      V, Q, P, 1024, 1024, 256, 262144, 262144, 1048576, -2.0 / 1024.0, 0.1 / 1024.0);

  // G = (1/1024^2) V^T @ V   (f64, 256x256)
  k_gemm_tn<float><<<dim3(4, 4, 8), 256, 0, stream>>>(
      V, V, G, 256, 256, 1024, 262144, 262144, 65536, 1.0 / 1048576.0);

  // Ad = I + 2G, X0 = I - 2G
  k_adx0<<<dim3(2048), 256, 0, stream>>>(G, Ad, X);

  // Newton-Schulz x3: X <- X(2I - Ad X); final M in X2
  for (int it = 0; it < 3; ++it) {
    const double* Xc = (it % 2 == 0) ? X : X2;
    double* Xn = (it % 2 == 0) ? X2 : X;
    k_smallmm<false><<<dim3(4, 4, 8), 256, 0, stream>>>(
        Ad, Xc, (const double*)nullptr, (void*)Y, 256, 65536, 65536, 1.0, 0.0);
    k_smallmm<false><<<dim3(4, 4, 8), 256, 0, stream>>>(
        Xc, Y, Xc, (void*)Xn, 256, 65536, 65536, -1.0, 2.0);
  }

  // PV64 = (1/1024) V^T @ P   (f64, 256x1024)
  k_gemm_tn<double><<<dim3(4, 16, 8), 256, 0, stream>>>(
      V, P, PV64, 256, 1024, 1024, 262144, 1048576, 262144, 1.0 / 1024.0);

  // PVP = M @ PV64  (fp32 out)
  k_smallmm<true><<<dim3(4, 16, 8), 256, 0, stream>>>(
      X2, PV64, (const double*)nullptr, (void*)PVP, 1024, 262144, 262144, 1.0, 0.0);

  // W1 = (1/1024) M @ V^T  (fp32 out, 256x1024)
  k_gemm_nt<double, float><<<dim3(4, 16, 8), 256, 0, stream>>>(
      X2, V, W1, 256, 1024, 256, 65536, 262144, 262144, 1.0 / 1024.0, 0.0);

  // paired transposes (PV64/X2 dead now): W1 (256x1024) -> W1T, V (1024x256) -> VT
  k_transpose_pair<<<dim3(8, 32, 8), 256, 0, stream>>>(W1, W1T, 256, 1024);
  k_transpose_pair<<<dim3(32, 8, 8), 256, 0, stream>>>(V, VT, 1024, 256);

  // 50 ADMM iterations, fully fused: 512 blocks x 512 threads
  k_persist<<<dim3(512), 512, 0, stream>>>(W1T, VT, PVP, P, E);

  // epilogue
  k_count<<<dim3(4, 8), 256, 0, stream>>>(E, INV);
  k_out<<<dim3(16, 2, 8), 256, 0, stream>>>(E, V, INV, out);
}

// Round 3
// 9988.895 us; speedup vs baseline: 1.1586x; 1.1586x over previous
//
#include <hip/hip_runtime.h>

// Problem constants (b=8, n=1024, m=1024, d=256, RHO=1, LAMBDA=0.1, 50 iters)
// ADMM box-QP via Woodbury on A = I + 2 Vs Vs^T  (Vs = V / 1024).
//   state e (f64):  z = clip(e), s = 2z - e
//   w  = W1 @ s - Pvp            (fp32, K=1024)   W1 = M Vs^T, Pvp = M Vs^T P
//   e' = clip(e) - P - (2/1024) * (V @ w)   (fp32 K=256 + f64 elementwise)
// Persistent kernel: block owns 16 columns for all 50 iters. Phase GEMMs use
// R=4 rows/lane register tiles (64 acc), K split across waves + deterministic
// LDS reduction tree; operands pre-swizzled for coalesced per-lane b128 loads.

__device__ __forceinline__ double clip01(double v) { return fmin(fmax(v, 0.0), 1.0); }

// ---------------- NT GEMM, f64 accumulate: C = (TC)(alpha * A@B^T + c0) ----------
template <typename TA, typename TC>
__global__ __launch_bounds__(256) void k_gemm_nt(
    const TA* __restrict__ Ag, const float* __restrict__ Bg, TC* __restrict__ Cg,
    int M, int N, int K, long sA, long sB, long sC, double alpha, double c0)
{
  const TA* A = Ag + (long)blockIdx.z * sA;
  const float* B = Bg + (long)blockIdx.z * sB;
  TC* C = Cg + (long)blockIdx.z * sC;
  const int m0 = blockIdx.x * 64, n0 = blockIdx.y * 64;
  const int tid = threadIdx.x;
  __shared__ double As[32][68];
  __shared__ double Bs[32][68];
  const int tx = tid & 15, ty = tid >> 4;
  const int r = tid >> 2, kq = (tid & 3) * 8;
  double acc[4][4] = {};
  for (int k0 = 0; k0 < K; k0 += 32) {
    if constexpr (sizeof(TA) == 4) {
      const float4* ap = reinterpret_cast<const float4*>(A + (size_t)(m0 + r) * K + k0 + kq);
      float4 a0 = ap[0], a1 = ap[1];
      As[kq+0][r] = a0.x; As[kq+1][r] = a0.y; As[kq+2][r] = a0.z; As[kq+3][r] = a0.w;
      As[kq+4][r] = a1.x; As[kq+5][r] = a1.y; As[kq+6][r] = a1.z; As[kq+7][r] = a1.w;
    } else {
      const double2* ap = reinterpret_cast<const double2*>(A + (size_t)(m0 + r) * K + k0 + kq);
      double2 a0 = ap[0], a1 = ap[1], a2 = ap[2], a3 = ap[3];
      As[kq+0][r] = a0.x; As[kq+1][r] = a0.y; As[kq+2][r] = a1.x; As[kq+3][r] = a1.y;
      As[kq+4][r] = a2.x; As[kq+5][r] = a2.y; As[kq+6][r] = a3.x; As[kq+7][r] = a3.y;
    }
    {
      const float4* bp = reinterpret_cast<const float4*>(B + (size_t)(n0 + r) * K + k0 + kq);
      float4 b0 = bp[0], b1 = bp[1];
      Bs[kq+0][r] = b0.x; Bs[kq+1][r] = b0.y; Bs[kq+2][r] = b0.z; Bs[kq+3][r] = b0.w;
      Bs[kq+4][r] = b1.x; Bs[kq+5][r] = b1.y; Bs[kq+6][r] = b1.z; Bs[kq+7][r] = b1.w;
    }
    __syncthreads();
#pragma unroll
    for (int kk = 0; kk < 32; ++kk) {
      double a_[4], b_[4];
#pragma unroll
      for (int i = 0; i < 4; ++i) a_[i] = As[kk][ty * 4 + i];
#pragma unroll
      for (int j = 0; j < 4; ++j) b_[j] = Bs[kk][tx * 4 + j];
#pragma unroll
      for (int i = 0; i < 4; ++i)
#pragma unroll
        for (int j = 0; j < 4; ++j) acc[i][j] = fma(a_[i], b_[j], acc[i][j]);
    }
    __syncthreads();
  }
#pragma unroll
  for (int i = 0; i < 4; ++i) {
    int row = m0 + ty * 4 + i;
#pragma unroll
    for (int j = 0; j < 4; ++j)
      C[(size_t)row * N + n0 + tx * 4 + j] = (TC)(alpha * acc[i][j] + c0);
  }
}

// ---------------- TN GEMM, f64 accumulate: C[MxN] = scale * A^T @ B -------------
template <typename TB>
__global__ __launch_bounds__(256) void k_gemm_tn(
    const float* __restrict__ Ag, const TB* __restrict__ Bg, double* __restrict__ Cg,
    int M, int N, int K, long sA, long sB, long sC, double scale)
{
  const float* A = Ag + (long)blockIdx.z * sA;
  const TB* B = Bg + (long)blockIdx.z * sB;
  double* C = Cg + (long)blockIdx.z * sC;
  const int m0 = blockIdx.x * 64, n0 = blockIdx.y * 64;
  const int tid = threadIdx.x;
  __shared__ float As[16][68];
  __shared__ double Bs[16][68];
  const int tx = tid & 15, ty = tid >> 4;
  const int kk = tid >> 4, c4 = (tid & 15) * 4;
  double acc[4][4] = {};
  for (int k0 = 0; k0 < K; k0 += 16) {
    float4 av = *reinterpret_cast<const float4*>(A + (size_t)(k0 + kk) * M + m0 + c4);
    *reinterpret_cast<float4*>(&As[kk][c4]) = av;
    if constexpr (sizeof(TB) == 4) {
      float4 bv = *reinterpret_cast<const float4*>(B + (size_t)(k0 + kk) * N + n0 + c4);
      Bs[kk][c4 + 0] = bv.x; Bs[kk][c4 + 1] = bv.y; Bs[kk][c4 + 2] = bv.z; Bs[kk][c4 + 3] = bv.w;
    } else {
      const double2* bp = reinterpret_cast<const double2*>(B + (size_t)(k0 + kk) * N + n0 + c4);
      double2 b0 = bp[0], b1 = bp[1];
      *reinterpret_cast<double2*>(&Bs[kk][c4]) = b0;
      *reinterpret_cast<double2*>(&Bs[kk][c4 + 2]) = b1;
    }
    __syncthreads();
#pragma unroll
    for (int k = 0; k < 16; ++k) {
      double a_[4], b_[4];
#pragma unroll
      for (int i = 0; i < 4; ++i) a_[i] = (double)As[k][ty * 4 + i];
#pragma unroll
      for (int j = 0; j < 4; ++j) b_[j] = Bs[k][tx * 4 + j];
#pragma unroll
      for (int i = 0; i < 4; ++i)
#pragma unroll
        for (int j = 0; j < 4; ++j) acc[i][j] = fma(a_[i], b_[j], acc[i][j]);
    }
    __syncthreads();
  }
#pragma unroll
  for (int i = 0; i < 4; ++i) {
    int row = m0 + ty * 4 + i;
#pragma unroll
    for (int j = 0; j < 4; ++j)
      C[(size_t)row * N + n0 + tx * 4 + j] = scale * acc[i][j];
  }
}

// ---------------- Ad = I + 2G, X0 = I - 2G --------------------------------------
__global__ __launch_bounds__(256) void k_adx0(const double* __restrict__ G,
                                              double* __restrict__ Ad, double* __restrict__ X)
{
  size_t idx = (size_t)blockIdx.x * 256 + threadIdx.x;
  double g = G[idx];
  int ij = (int)(idx & 65535);
  double dg = ((ij >> 8) == (ij & 255)) ? 1.0 : 0.0;
  Ad[idx] = dg + 2.0 * g;
  X[idx] = dg - 2.0 * g;
}

// ---------------- small f64 NN GEMM: C = alpha*A@B + beta*Xin -------------------
template <bool F32OUT>
__global__ __launch_bounds__(256) void k_smallmm(
    const double* __restrict__ Ag, const double* __restrict__ Bg,
    const double* __restrict__ Xg, void* __restrict__ Cg,
    int N, long sB, long sC, double alpha, double beta)
{
  const double* A = Ag + (long)blockIdx.z * 65536;
  const double* B = Bg + (long)blockIdx.z * sB;
  const double* Xp = Xg ? (Xg + (long)blockIdx.z * sB) : (const double*)nullptr;
  const int m0 = blockIdx.x * 64, n0 = blockIdx.y * 64;
  const int tid = threadIdx.x;
  __shared__ double As[16][68];
  __shared__ double Bs[16][68];
  const int tx = tid & 15, ty = tid >> 4;
  const int ra = tid >> 2, kqa = (tid & 3) * 4;
  const int kb = tid >> 4, cb = (tid & 15) * 4;
  double acc[4][4] = {};
  for (int k0 = 0; k0 < 256; k0 += 16) {
    const double2* ap = reinterpret_cast<const double2*>(A + (size_t)(m0 + ra) * 256 + k0 + kqa);
    double2 a0 = ap[0], a1 = ap[1];
    As[kqa + 0][ra] = a0.x; As[kqa + 1][ra] = a0.y; As[kqa + 2][ra] = a1.x; As[kqa + 3][ra] = a1.y;
    const double2* bp = reinterpret_cast<const double2*>(B + (size_t)(k0 + kb) * N + n0 + cb);
    double2 b0 = bp[0], b1 = bp[1];
    *reinterpret_cast<double2*>(&Bs[kb][cb]) = b0;
    *reinterpret_cast<double2*>(&Bs[kb][cb + 2]) = b1;
    __syncthreads();
#pragma unroll
    for (int k = 0; k < 16; ++k) {
      double a_[4], b_[4];
#pragma unroll
      for (int i = 0; i < 4; ++i) a_[i] = As[k][ty * 4 + i];
#pragma unroll
      for (int j = 0; j < 4; ++j) b_[j] = Bs[k][tx * 4 + j];
#pragma unroll
      for (int i = 0; i < 4; ++i)
#pragma unroll
        for (int j = 0; j < 4; ++j) acc[i][j] = fma(a_[i], b_[j], acc[i][j]);
    }
    __syncthreads();
  }
#pragma unroll
  for (int i = 0; i < 4; ++i) {
    int row = m0 + ty * 4 + i;
#pragma unroll
    for (int j = 0; j < 4; ++j) {
      int col = n0 + tx * 4 + j;
      double v = alpha * acc[i][j];
      if (beta != 0.0) v = fma(beta, Xp[(size_t)row * N + col], v);
      if constexpr (F32OUT)
        ((float*)Cg)[(long)blockIdx.z * sC + (size_t)row * N + col] = (float)v;
      else
        ((double*)Cg)[(long)blockIdx.z * sC + (size_t)row * N + col] = v;
    }
  }
}

// ---------------- swizzled transpose ---------------------------------------------
// in: (R,C) f32 row-major.  out[k][ 256*(r>>8) + 4*(r&63) + ((r>>6)&3) ] = in[r][k]
// (for R=256 this is out[k][4*(r&63)+(r>>6)]). Pure data movement.
__global__ __launch_bounds__(256) void k_swzT(
    const float* __restrict__ in, float* __restrict__ out, int R, int C)
{
  __shared__ float t[32][33];
  const float* ip = in + (size_t)blockIdx.z * R * C;
  float* op = out + (size_t)blockIdx.z * R * C;
  const int r0 = blockIdx.x * 32, c0 = blockIdx.y * 32;
  const int tx = threadIdx.x & 31, ty = threadIdx.x >> 5;
#pragma unroll
  for (int i = 0; i < 4; ++i)
    t[ty + i * 8][tx] = ip[(size_t)(r0 + ty + i * 8) * C + c0 + tx];
  __syncthreads();
#pragma unroll
  for (int i = 0; i < 4; ++i) {
    int k = c0 + ty + i * 8;
    int r = r0 + tx;
    int m = ((r >> 8) << 8) + 4 * (r & 63) + ((r >> 6) & 3);
    op[(size_t)k * R + m] = t[tx][ty + i * 8];
  }
}

// ---------------- persistent ADMM kernel -----------------------------------------
// 512 threads = 8 waves, block = (batch b = bid&7, 16 cols j0). 1 block/CU.
// Phase 1: each wave: ALL 256 w-rows x 16 cols (R=4/lane), K-chunk 128 -> tree-reduce.
// Phase 2: wave pairs (w, w+4): 256 g-rows x 16 cols, K split 2 -> pair-reduce.
// s,w in LDS (stride-20 rows, conflict-free); e in VGPRs of waves 0-3.
__global__ __launch_bounds__(512, 2) void k_persist2(
    const float* __restrict__ W1s, const float* __restrict__ Vs,
    const float* __restrict__ PVPg, const double* __restrict__ Pg,
    double* __restrict__ Eg)
{
  const int bid = blockIdx.x;
  const int b = bid & 7;
  const int j0 = (bid >> 3) << 4;
  const float* W1p = W1s + (size_t)b * 262144;   // swizzled [1024][256]
  const float* Vp  = Vs  + (size_t)b * 262144;   // swizzled [256][1024]
  const float* Pvp = PVPg + (size_t)b * 262144;  // [256][1024]
  const double* P  = Pg + (size_t)b * 1048576 + j0;
  double* E        = Eg + (size_t)b * 1048576 + j0;

  const int tid = threadIdx.x;
  const int w   = tid >> 6;   // wave 0..7
  const int l   = tid & 63;   // lane

  __shared__ __align__(16) float s_ld[1024 * 20];  // 80 KB, row stride 20
  __shared__ __align__(16) float w_ld[256 * 20];   // 20 KB, row stride 20
  float* RED = s_ld;  // overlay: 4 slots x (64 lanes x 68 floats)

  // zero s
  for (int i = tid; i < 1024 * 20; i += 512) s_ld[i] = 0.0f;

  // e state: wave W<4, lane l owns rows 256*W + 64*t + l (t=0..3), cols 0..15
  double e[4][16];
#pragma unroll
  for (int t = 0; t < 4; ++t)
#pragma unroll
    for (int c = 0; c < 16; ++c) e[t][c] = 0.0;

  const double cg = 2.0 / 1024.0;
  float* slot = RED + (w & 3) * 4352 + l * 68;   // my reduction slot
  __syncthreads();

  for (int it = 0; it < 50; ++it) {
    // ================= phase 1: partial w = W1[:,chunk] @ s[chunk,:] ==========
    float acc[4][16];
#pragma unroll
    for (int t = 0; t < 4; ++t)
#pragma unroll
      for (int c = 0; c < 16; ++c) acc[t][c] = 0.0f;
    {
      const int k0 = w * 128;
      const float* w1ptr = W1p + (size_t)k0 * 256 + 4 * l;
#pragma unroll 2
      for (int k = 0; k < 128; ++k) {
        const float4* srow = reinterpret_cast<const float4*>(&s_ld[(k0 + k) * 20]);
        float4 s0 = srow[0], s1 = srow[1], s2 = srow[2], s3 = srow[3];
        float4 a = *reinterpret_cast<const float4*>(w1ptr + (size_t)k * 256);
        float av[4] = {a.x, a.y, a.z, a.w};
        float sv[16] = {s0.x, s0.y, s0.z, s0.w, s1.x, s1.y, s1.z, s1.w,
                        s2.x, s2.y, s2.z, s2.w, s3.x, s3.y, s3.z, s3.w};
#pragma unroll
        for (int t = 0; t < 4; ++t)
#pragma unroll
          for (int c = 0; c < 16; ++c) acc[t][c] = fmaf(av[t], sv[c], acc[t][c]);
      }
    }
    __syncthreads();                       // all p1 sweeps done; s region free

    // reduction tree: ((c0+c4)+(c2+c6)) + ((c1+c5)+(c3+c7)), per chunk-index
    // round A: waves 4-7 -> slots 0-3; waves 0-3 add
    if (w >= 4) {
#pragma unroll
      for (int t = 0; t < 4; ++t)
#pragma unroll
        for (int q = 0; q < 4; ++q) {
          float4 v; v.x = acc[t][q*4]; v.y = acc[t][q*4+1]; v.z = acc[t][q*4+2]; v.w = acc[t][q*4+3];
          *reinterpret_cast<float4*>(slot + t * 16 + q * 4) = v;
        }
    }
    __syncthreads();
    if (w < 4) {
#pragma unroll
      for (int t = 0; t < 4; ++t)
#pragma unroll
        for (int q = 0; q < 4; ++q) {
          float4 v = *reinterpret_cast<const float4*>(slot + t * 16 + q * 4);
          acc[t][q*4] += v.x; acc[t][q*4+1] += v.y; acc[t][q*4+2] += v.z; acc[t][q*4+3] += v.w;
        }
    }
    __syncthreads();
    // round B: waves 2-3 -> slots 0-1; waves 0-1 add
    if (w == 2 || w == 3) {
      float* s2p = RED + (w - 2) * 4352 + l * 68;
#pragma unroll
      for (int t = 0; t < 4; ++t)
#pragma unroll
        for (int q = 0; q < 4; ++q) {
          float4 v; v.x = acc[t][q*4]; v.y = acc[t][q*4+1]; v.z = acc[t][q*4+2]; v.w = acc[t][q*4+3];
          *reinterpret_cast<float4*>(s2p + t * 16 + q * 4) = v;
        }
    }
    __syncthreads();
    if (w < 2) {
#pragma unroll
      for (int t = 0; t < 4; ++t)
#pragma unroll
        for (int q = 0; q < 4; ++q) {
          float4 v = *reinterpret_cast<const float4*>(slot + t * 16 + q * 4);
          acc[t][q*4] += v.x; acc[t][q*4+1] += v.y; acc[t][q*4+2] += v.z; acc[t][q*4+3] += v.w;
        }
    }
    __syncthreads();
    // round C: wave 1 -> slot 0; wave 0 adds, subtracts Pvp, stores w_ld
    if (w == 1) {
      float* s0p = RED + l * 68;
#pragma unroll
      for (int t = 0; t < 4; ++t)
#pragma unroll
        for (int q = 0; q < 4; ++q) {
          float4 v; v.x = acc[t][q*4]; v.y = acc[t][q*4+1]; v.z = acc[t][q*4+2]; v.w = acc[t][q*4+3];
          *reinterpret_cast<float4*>(s0p + t * 16 + q * 4) = v;
        }
    }
    __syncthreads();
    if (w == 0) {
#pragma unroll
      for (int t = 0; t < 4; ++t) {
        const int row = l + 64 * t;
        const float* pvrow = Pvp + (size_t)row * 1024 + j0;
        float* wrow = &w_ld[row * 20];
#pragma unroll
        for (int q = 0; q < 4; ++q) {
          float4 v = *reinterpret_cast<const float4*>(slot + t * 16 + q * 4);
          float4 pv = *reinterpret_cast<const float4*>(pvrow + q * 4);
          float4 o;
          o.x = acc[t][q*4]   + v.x - pv.x;
          o.y = acc[t][q*4+1] + v.y - pv.y;
          o.z = acc[t][q*4+2] + v.z - pv.z;
          o.w = acc[t][q*4+3] + v.w - pv.w;
          *reinterpret_cast<float4*>(wrow + q * 4) = o;
        }
      }
    }
    __syncthreads();                       // w_ld ready

    // ================= phase 2: g = V @ w, rows 256*(w&3).., K split 2 ========
    float g[4][16];
#pragma unroll
    for (int t = 0; t < 4; ++t)
#pragma unroll
      for (int c = 0; c < 16; ++c) g[t][c] = 0.0f;
    {
      const int G = w & 3;
      const int kb = (w >> 2) * 128;
      const float* vptr = Vp + (size_t)kb * 1024 + 256 * G + 4 * l;
#pragma unroll 2
      for (int k = 0; k < 128; ++k) {
        const float4* wrow = reinterpret_cast<const float4*>(&w_ld[(kb + k) * 20]);
        float4 q0 = wrow[0], q1 = wrow[1], q2 = wrow[2], q3 = wrow[3];
        float4 a = *reinterpret_cast<const float4*>(vptr + (size_t)k * 1024);
        float av[4] = {a.x, a.y, a.z, a.w};
        float wv[16] = {q0.x, q0.y, q0.z, q0.w, q1.x, q1.y, q1.z, q1.w,
                        q2.x, q2.y, q2.z, q2.w, q3.x, q3.y, q3.z, q3.w};
#pragma unroll
        for (int t = 0; t < 4; ++t)
#pragma unroll
          for (int c = 0; c < 16; ++c) g[t][c] = fmaf(av[t], wv[c], g[t][c]);
      }
    }
    // waves 4-7 (high-K chunk) write partials; waves 0-3 add (lo + hi)
    if (w >= 4) {
#pragma unroll
      for (int t = 0; t < 4; ++t)
#pragma unroll
        for (int q = 0; q < 4; ++q) {
          float4 v; v.x = g[t][q*4]; v.y = g[t][q*4+1]; v.z = g[t][q*4+2]; v.w = g[t][q*4+3];
          *reinterpret_cast<float4*>(slot + t * 16 + q * 4) = v;
        }
    }
    __syncthreads();
    if (w < 4) {
#pragma unroll
      for (int t = 0; t < 4; ++t)
#pragma unroll
        for (int q = 0; q < 4; ++q) {
          float4 v = *reinterpret_cast<const float4*>(slot + t * 16 + q * 4);
          g[t][q*4] += v.x; g[t][q*4+1] += v.y; g[t][q*4+2] += v.z; g[t][q*4+3] += v.w;
        }
    }
    __syncthreads();                       // RED reads done; s region writable

    // ================= elementwise (waves 0-3) ================================
    if (w < 4) {
#pragma unroll
      for (int t = 0; t < 4; ++t) {
        const int row = 256 * w + 64 * t + l;
        const double* prow = P + (size_t)row * 1024;
        double p_[16];
#pragma unroll
        for (int q = 0; q < 8; ++q) {
          double2 pv = *reinterpret_cast<const double2*>(prow + 2 * q);
          p_[2*q] = pv.x; p_[2*q+1] = pv.y;
        }
        float s_[16];
#pragma unroll
        for (int c = 0; c < 16; ++c) {
          double z = clip01(e[t][c]);
          double en = z - p_[c] - cg * (double)g[t][c];
          e[t][c] = en;
          s_[c] = (float)(2.0 * clip01(en) - en);
        }
        float* srow = &s_ld[row * 20];
#pragma unroll
        for (int q = 0; q < 4; ++q) {
          float4 v; v.x = s_[q*4]; v.y = s_[q*4+1]; v.z = s_[q*4+2]; v.w = s_[q*4+3];
          *reinterpret_cast<float4*>(srow + q * 4) = v;
        }
      }
    }
    __syncthreads();                       // s ready for next iter
  }

  // final E store (waves 0-3)
  if (w < 4) {
#pragma unroll
    for (int t = 0; t < 4; ++t) {
      const int row = 256 * w + 64 * t + l;
      double* erow = E + (size_t)row * 1024;
#pragma unroll
      for (int q = 0; q < 8; ++q) {
        double2 v; v.x = e[t][2*q]; v.y = e[t][2*q+1];
        *reinterpret_cast<double2*>(erow + 2 * q) = v;
      }
    }
  }
}

// ---------------- per-(b,n) count -> inverse scale ------------------------------
__global__ __launch_bounds__(256) void k_count(const double* __restrict__ Eg, float* __restrict__ inv)
{
  const int bz = blockIdx.y;
  const int j = blockIdx.x * 256 + threadIdx.x;
  const double* E = Eg + (size_t)bz * 1048576;
  int c = 0;
  for (int i = 0; i < 1024; ++i) c += (E[(size_t)i * 1024 + j] > 0.5) ? 1 : 0;
  inv[bz * 1024 + j] = (float)(1.0 / (((double)c) + 1e-10) / 1024.0);
}

// ---------------- output masked GEMM: out[j,dd] = inv[j] * sum_i mask(e) V[i,dd] --
__global__ __launch_bounds__(256) void k_out(
    const double* __restrict__ Eg, const float* __restrict__ Vg,
    const float* __restrict__ invg, float* __restrict__ Og)
{
  const double* E = Eg + (size_t)blockIdx.z * 1048576;
  const float* Vv = Vg + (size_t)blockIdx.z * 262144;
  const float* inv = invg + blockIdx.z * 1024;
  float* O = Og + (size_t)blockIdx.z * 262144;
  const int j0 = blockIdx.x * 64, d0 = blockIdx.y * 128;
  const int tid = threadIdx.x;
  __shared__ float As[32][68];
  __shared__ float Bs[32][132];
  const int tx = tid & 15, ty = tid >> 4;
  const int ka = tid >> 3, ja = (tid & 7) * 8;
  const int rb = tid >> 5, cb = (tid & 31) * 4;
  float acc[4][8] = {};
  for (int k0 = 0; k0 < 1024; k0 += 32) {
    {
      const double2* ep = reinterpret_cast<const double2*>(E + (size_t)(k0 + ka) * 1024 + j0 + ja);
      double2 e0 = ep[0], e1 = ep[1], e2 = ep[2], e3 = ep[3];
      As[ka][ja + 0] = (e0.x > 0.5) ? 1.0f : 0.0f;
      As[ka][ja + 1] = (e0.y > 0.5) ? 1.0f : 0.0f;
      As[ka][ja + 2] = (e1.x > 0.5) ? 1.0f : 0.0f;
      As[ka][ja + 3] = (e1.y > 0.5) ? 1.0f : 0.0f;
      As[ka][ja + 4] = (e2.x > 0.5) ? 1.0f : 0.0f;
      As[ka][ja + 5] = (e2.y > 0.5) ? 1.0f : 0.0f;
      As[ka][ja + 6] = (e3.x > 0.5) ? 1.0f : 0.0f;
      As[ka][ja + 7] = (e3.y > 0.5) ? 1.0f : 0.0f;
    }
#pragma unroll
    for (int p = 0; p < 4; ++p) {
      int krow = rb + p * 8;
      float4 bv = *reinterpret_cast<const float4*>(Vv + (size_t)(k0 + krow) * 256 + d0 + cb);
      *reinterpret_cast<float4*>(&Bs[krow][cb]) = bv;
    }
    __syncthreads();
#pragma unroll
    for (int kk = 0; kk < 32; ++kk) {
      float4 av = *reinterpret_cast<const float4*>(&As[kk][ty * 4]);
      float4 b0 = *reinterpret_cast<const float4*>(&Bs[kk][tx * 8]);
      float4 b1 = *reinterpret_cast<const float4*>(&Bs[kk][tx * 8 + 4]);
      float a_[4] = {av.x, av.y, av.z, av.w};
      float b_[8] = {b0.x, b0.y, b0.z, b0.w, b1.x, b1.y, b1.z, b1.w};
#pragma unroll
      for (int i = 0; i < 4; ++i)
#pragma unroll
        for (int j = 0; j < 8; ++j) acc[i][j] = fmaf(a_[i], b_[j], acc[i][j]);
    }
    __syncthreads();
  }
#pragma unroll
  for (int i = 0; i < 4; ++i) {
    int row = j0 + ty * 4 + i;
    float sc = inv[row];
    size_t base = (size_t)row * 256 + d0 + tx * 8;
    float4 o0 = {acc[i][0] * sc, acc[i][1] * sc, acc[i][2] * sc, acc[i][3] * sc};
    float4 o1 = {acc[i][4] * sc, acc[i][5] * sc, acc[i][6] * sc, acc[i][7] * sc};
    *reinterpret_cast<float4*>(O + base) = o0;
    *reinterpret_cast<float4*>(O + base + 4) = o1;
  }
}

extern "C" void kernel_launch(void* const* d_in, const int* in_sizes, int n_in,
                              void* d_out, int out_size, void* d_ws, size_t ws_size,
                              hipStream_t stream)
{
  const float* Q = (const float*)d_in[0];   // (8,1024,256)
  const float* V = (const float*)d_in[1];   // (8,1024,256)
  float* out = (float*)d_out;               // (8,1024,256)
  char* ws = (char*)d_ws;

  // workspace layout (bytes) — total ~193 MB
  const size_t OFF_E   = 0;                  // e final, f64 (8,1024,1024)
  const size_t OFF_P   = 67108864;           // P, f64 (8,1024,1024)
  const size_t SCR     = 134217728;          // scratch region
  const size_t OFF_G   = SCR;
  const size_t OFF_AD  = SCR + 4194304;
  const size_t OFF_X   = SCR + 8388608;
  const size_t OFF_Y   = SCR + 12582912;
  const size_t OFF_X2  = SCR + 16777216;     // final M
  const size_t OFF_PV64= SCR;                // f64 (8,256,1024) overlays G..Y
  const size_t OFF_W1Z = SCR;                // fp32 swizzled W1 (8MB) — after PV64 dead
  const size_t OFF_VZ  = SCR + 8388608;      // fp32 swizzled V (8MB)
  const size_t OFF_W1  = 176160768;          // fp32 W1 (8,256,1024)
  const size_t OFF_PVP = 184549376;          // fp32 Pvp (8,256,1024)
  const size_t OFF_INV = 192937984;          // fp32 (8,1024)

  double* E    = (double*)(ws + OFF_E);
  double* P    = (double*)(ws + OFF_P);
  double* G    = (double*)(ws + OFF_G);
  double* Ad   = (double*)(ws + OFF_AD);
  double* X    = (double*)(ws + OFF_X);
  double* Y    = (double*)(ws + OFF_Y);
  double* X2   = (double*)(ws + OFF_X2);
  double* PV64 = (double*)(ws + OFF_PV64);
  float*  W1Z  = (float*)(ws + OFF_W1Z);
  float*  VZ   = (float*)(ws + OFF_VZ);
  float*  W1   = (float*)(ws + OFF_W1);
  float*  PVP  = (float*)(ws + OFF_PVP);
  float*  INV  = (float*)(ws + OFF_INV);

  (void)in_sizes; (void)n_in; (void)out_size; (void)ws_size;

  // P = (-2/1024) * V @ Q^T + 0.1/1024     (f64, K=256)
  k_gemm_nt<float, double><<<dim3(16, 16, 8), 256, 0, stream>>>(
      V, Q, P, 1024, 1024, 256, 262144, 262144, 1048576, -2.0 / 1024.0, 0.1 / 1024.0);

  // G = (1/1024^2) V^T @ V   (f64, 256x256)
  k_gemm_tn<float><<<dim3(4, 4, 8), 256, 0, stream>>>(
      V, V, G, 256, 256, 1024, 262144, 262144, 65536, 1.0 / 1048576.0);

  // Ad = I + 2G, X0 = I - 2G
  k_adx0<<<dim3(2048), 256, 0, stream>>>(G, Ad, X);

  // Newton-Schulz x3: X <- X(2I - Ad X); final M in X2
  for (int it = 0; it < 3; ++it) {
    const double* Xc = (it % 2 == 0) ? X : X2;
    double* Xn = (it % 2 == 0) ? X2 : X;
    k_smallmm<false><<<dim3(4, 4, 8), 256, 0, stream>>>(
        Ad, Xc, (const double*)nullptr, (void*)Y, 256, 65536, 65536, 1.0, 0.0);
    k_smallmm<false><<<dim3(4, 4, 8), 256, 0, stream>>>(
        Xc, Y, Xc, (void*)Xn, 256, 65536, 65536, -1.0, 2.0);
  }

  // PV64 = (1/1024) V^T @ P   (f64, 256x1024)
  k_gemm_tn<double><<<dim3(4, 16, 8), 256, 0, stream>>>(
      V, P, PV64, 256, 1024, 1024, 262144, 1048576, 262144, 1.0 / 1024.0);

  // PVP = M @ PV64  (fp32 out)
  k_smallmm<true><<<dim3(4, 16, 8), 256, 0, stream>>>(
      X2, PV64, (const double*)nullptr, (void*)PVP, 1024, 262144, 262144, 1.0, 0.0);

  // W1 = (1/1024) M @ V^T  (fp32 out, 256x1024)
  k_gemm_nt<double, float><<<dim3(4, 16, 8), 256, 0, stream>>>(
      X2, V, W1, 256, 1024, 256, 65536, 262144, 262144, 1.0 / 1024.0, 0.0);

  // swizzled operand layouts (PV64/X2 dead now)
  k_swzT<<<dim3(8, 32, 8), 256, 0, stream>>>(W1, W1Z, 256, 1024);
  k_swzT<<<dim3(32, 8, 8), 256, 0, stream>>>(V, VZ, 1024, 256);

  // 50 ADMM iterations, persistent: 512 blocks x 512 threads (1 block/CU)
  k_persist2<<<dim3(512), 512, 0, stream>>>(W1Z, VZ, PVP, P, E);

  // epilogue
  k_count<<<dim3(4, 8), 256, 0, stream>>>(E, INV);
  k_out<<<dim3(16, 2, 8), 256, 0, stream>>>(E, V, INV, out);
}

// Round 5
// 9368.184 us; speedup vs baseline: 1.2353x; 1.0663x over previous
//
#include <hip/hip_runtime.h>

// Problem constants (b=8, n=1024, m=1024, d=256, RHO=1, LAMBDA=0.1, 50 iters)
// ADMM box-QP via Woodbury on A = I + 2 Vs Vs^T  (Vs = V / 1024).
//   state e (f64):  z = clip(e), s = 2z - e
//   w  = W1 @ s - Pvp            (fp32, K=1024)   W1 = M Vs^T, Pvp = M Vs^T P
//   e' = clip(e) - P - (2/1024) * (V @ w)   (fp32 K=256 + f64 elementwise)
// Persistent kernel: block owns 8 columns for all 50 iters (2 blocks/CU,
// 16 waves/CU). Phase GEMMs: R=4 rows/lane, K split across waves +
// deterministic LDS tree; operands pre-swizzled for coalesced b128 loads.
// Math bitwise-identical to round 3 (same k-order, same tree).

__device__ __forceinline__ double clip01(double v) { return fmin(fmax(v, 0.0), 1.0); }

// ---------------- NT GEMM, f64 accumulate: C = (TC)(alpha * A@B^T + c0) ----------
template <typename TA, typename TC>
__global__ __launch_bounds__(256) void k_gemm_nt(
    const TA* __restrict__ Ag, const float* __restrict__ Bg, TC* __restrict__ Cg,
    int M, int N, int K, long sA, long sB, long sC, double alpha, double c0)
{
  const TA* A = Ag + (long)blockIdx.z * sA;
  const float* B = Bg + (long)blockIdx.z * sB;
  TC* C = Cg + (long)blockIdx.z * sC;
  const int m0 = blockIdx.x * 64, n0 = blockIdx.y * 64;
  const int tid = threadIdx.x;
  __shared__ double As[32][68];
  __shared__ double Bs[32][68];
  const int tx = tid & 15, ty = tid >> 4;
  const int r = tid >> 2, kq = (tid & 3) * 8;
  double acc[4][4] = {};
  for (int k0 = 0; k0 < K; k0 += 32) {
    if constexpr (sizeof(TA) == 4) {
      const float4* ap = reinterpret_cast<const float4*>(A + (size_t)(m0 + r) * K + k0 + kq);
      float4 a0 = ap[0], a1 = ap[1];
      As[kq+0][r] = a0.x; As[kq+1][r] = a0.y; As[kq+2][r] = a0.z; As[kq+3][r] = a0.w;
      As[kq+4][r] = a1.x; As[kq+5][r] = a1.y; As[kq+6][r] = a1.z; As[kq+7][r] = a1.w;
    } else {
      const double2* ap = reinterpret_cast<const double2*>(A + (size_t)(m0 + r) * K + k0 + kq);
      double2 a0 = ap[0], a1 = ap[1], a2 = ap[2], a3 = ap[3];
      As[kq+0][r] = a0.x; As[kq+1][r] = a0.y; As[kq+2][r] = a1.x; As[kq+3][r] = a1.y;
      As[kq+4][r] = a2.x; As[kq+5][r] = a2.y; As[kq+6][r] = a3.x; As[kq+7][r] = a3.y;
    }
    {
      const float4* bp = reinterpret_cast<const float4*>(B + (size_t)(n0 + r) * K + k0 + kq);
      float4 b0 = bp[0], b1 = bp[1];
      Bs[kq+0][r] = b0.x; Bs[kq+1][r] = b0.y; Bs[kq+2][r] = b0.z; Bs[kq+3][r] = b0.w;
      Bs[kq+4][r] = b1.x; Bs[kq+5][r] = b1.y; Bs[kq+6][r] = b1.z; Bs[kq+7][r] = b1.w;
    }
    __syncthreads();
#pragma unroll
    for (int kk = 0; kk < 32; ++kk) {
      double a_[4], b_[4];
#pragma unroll
      for (int i = 0; i < 4; ++i) a_[i] = As[kk][ty * 4 + i];
#pragma unroll
      for (int j = 0; j < 4; ++j) b_[j] = Bs[kk][tx * 4 + j];
#pragma unroll
      for (int i = 0; i < 4; ++i)
#pragma unroll
        for (int j = 0; j < 4; ++j) acc[i][j] = fma(a_[i], b_[j], acc[i][j]);
    }
    __syncthreads();
  }
#pragma unroll
  for (int i = 0; i < 4; ++i) {
    int row = m0 + ty * 4 + i;
#pragma unroll
    for (int j = 0; j < 4; ++j)
      C[(size_t)row * N + n0 + tx * 4 + j] = (TC)(alpha * acc[i][j] + c0);
  }
}

// ---------------- TN GEMM, f64 accumulate: C[MxN] = scale * A^T @ B -------------
template <typename TB>
__global__ __launch_bounds__(256) void k_gemm_tn(
    const float* __restrict__ Ag, const TB* __restrict__ Bg, double* __restrict__ Cg,
    int M, int N, int K, long sA, long sB, long sC, double scale)
{
  const float* A = Ag + (long)blockIdx.z * sA;
  const TB* B = Bg + (long)blockIdx.z * sB;
  double* C = Cg + (long)blockIdx.z * sC;
  const int m0 = blockIdx.x * 64, n0 = blockIdx.y * 64;
  const int tid = threadIdx.x;
  __shared__ float As[16][68];
  __shared__ double Bs[16][68];
  const int tx = tid & 15, ty = tid >> 4;
  const int kk = tid >> 4, c4 = (tid & 15) * 4;
  double acc[4][4] = {};
  for (int k0 = 0; k0 < K; k0 += 16) {
    float4 av = *reinterpret_cast<const float4*>(A + (size_t)(k0 + kk) * M + m0 + c4);
    *reinterpret_cast<float4*>(&As[kk][c4]) = av;
    if constexpr (sizeof(TB) == 4) {
      float4 bv = *reinterpret_cast<const float4*>(B + (size_t)(k0 + kk) * N + n0 + c4);
      Bs[kk][c4 + 0] = bv.x; Bs[kk][c4 + 1] = bv.y; Bs[kk][c4 + 2] = bv.z; Bs[kk][c4 + 3] = bv.w;
    } else {
      const double2* bp = reinterpret_cast<const double2*>(B + (size_t)(k0 + kk) * N + n0 + c4);
      double2 b0 = bp[0], b1 = bp[1];
      *reinterpret_cast<double2*>(&Bs[kk][c4]) = b0;
      *reinterpret_cast<double2*>(&Bs[kk][c4 + 2]) = b1;
    }
    __syncthreads();
#pragma unroll
    for (int k = 0; k < 16; ++k) {
      double a_[4], b_[4];
#pragma unroll
      for (int i = 0; i < 4; ++i) a_[i] = (double)As[k][ty * 4 + i];
#pragma unroll
      for (int j = 0; j < 4; ++j) b_[j] = Bs[k][tx * 4 + j];
#pragma unroll
      for (int i = 0; i < 4; ++i)
#pragma unroll
        for (int j = 0; j < 4; ++j) acc[i][j] = fma(a_[i], b_[j], acc[i][j]);
    }
    __syncthreads();
  }
#pragma unroll
  for (int i = 0; i < 4; ++i) {
    int row = m0 + ty * 4 + i;
#pragma unroll
    for (int j = 0; j < 4; ++j)
      C[(size_t)row * N + n0 + tx * 4 + j] = scale * acc[i][j];
  }
}

// ---------------- Ad = I + 2G, X0 = I - 2G --------------------------------------
__global__ __launch_bounds__(256) void k_adx0(const double* __restrict__ G,
                                              double* __restrict__ Ad, double* __restrict__ X)
{
  size_t idx = (size_t)blockIdx.x * 256 + threadIdx.x;
  double g = G[idx];
  int ij = (int)(idx & 65535);
  double dg = ((ij >> 8) == (ij & 255)) ? 1.0 : 0.0;
  Ad[idx] = dg + 2.0 * g;
  X[idx] = dg - 2.0 * g;
}

// ---------------- small f64 NN GEMM: C = alpha*A@B + beta*Xin -------------------
template <bool F32OUT>
__global__ __launch_bounds__(256) void k_smallmm(
    const double* __restrict__ Ag, const double* __restrict__ Bg,
    const double* __restrict__ Xg, void* __restrict__ Cg,
    int N, long sB, long sC, double alpha, double beta)
{
  const double* A = Ag + (long)blockIdx.z * 65536;
  const double* B = Bg + (long)blockIdx.z * sB;
  const double* Xp = Xg ? (Xg + (long)blockIdx.z * sB) : (const double*)nullptr;
  const int m0 = blockIdx.x * 64, n0 = blockIdx.y * 64;
  const int tid = threadIdx.x;
  __shared__ double As[16][68];
  __shared__ double Bs[16][68];
  const int tx = tid & 15, ty = tid >> 4;
  const int ra = tid >> 2, kqa = (tid & 3) * 4;
  const int kb = tid >> 4, cb = (tid & 15) * 4;
  double acc[4][4] = {};
  for (int k0 = 0; k0 < 256; k0 += 16) {
    const double2* ap = reinterpret_cast<const double2*>(A + (size_t)(m0 + ra) * 256 + k0 + kqa);
    double2 a0 = ap[0], a1 = ap[1];
    As[kqa + 0][ra] = a0.x; As[kqa + 1][ra] = a0.y; As[kqa + 2][ra] = a1.x; As[kqa + 3][ra] = a1.y;
    const double2* bp = reinterpret_cast<const double2*>(B + (size_t)(k0 + kb) * N + n0 + cb);
    double2 b0 = bp[0], b1 = bp[1];
    *reinterpret_cast<double2*>(&Bs[kb][cb]) = b0;
    *reinterpret_cast<double2*>(&Bs[kb][cb + 2]) = b1;
    __syncthreads();
#pragma unroll
    for (int k = 0; k < 16; ++k) {
      double a_[4], b_[4];
#pragma unroll
      for (int i = 0; i < 4; ++i) a_[i] = As[k][ty * 4 + i];
#pragma unroll
      for (int j = 0; j < 4; ++j) b_[j] = Bs[k][tx * 4 + j];
#pragma unroll
      for (int i = 0; i < 4; ++i)
#pragma unroll
        for (int j = 0; j < 4; ++j) acc[i][j] = fma(a_[i], b_[j], acc[i][j]);
    }
    __syncthreads();
  }
#pragma unroll
  for (int i = 0; i < 4; ++i) {
    int row = m0 + ty * 4 + i;
#pragma unroll
    for (int j = 0; j < 4; ++j) {
      int col = n0 + tx * 4 + j;
      double v = alpha * acc[i][j];
      if (beta != 0.0) v = fma(beta, Xp[(size_t)row * N + col], v);
      if constexpr (F32OUT)
        ((float*)Cg)[(long)blockIdx.z * sC + (size_t)row * N + col] = (float)v;
      else
        ((double*)Cg)[(long)blockIdx.z * sC + (size_t)row * N + col] = v;
    }
  }
}

// ---------------- swizzled transpose ---------------------------------------------
// in: (R,C) f32 row-major.  out[k][ 256*(r>>8) + 4*(r&63) + ((r>>6)&3) ] = in[r][k]
__global__ __launch_bounds__(256) void k_swzT(
    const float* __restrict__ in, float* __restrict__ out, int R, int C)
{
  __shared__ float t[32][33];
  const float* ip = in + (size_t)blockIdx.z * R * C;
  float* op = out + (size_t)blockIdx.z * R * C;
  const int r0 = blockIdx.x * 32, c0 = blockIdx.y * 32;
  const int tx = threadIdx.x & 31, ty = threadIdx.x >> 5;
#pragma unroll
  for (int i = 0; i < 4; ++i)
    t[ty + i * 8][tx] = ip[(size_t)(r0 + ty + i * 8) * C + c0 + tx];
  __syncthreads();
#pragma unroll
  for (int i = 0; i < 4; ++i) {
    int k = c0 + ty + i * 8;
    int r = r0 + tx;
    int m = ((r >> 8) << 8) + 4 * (r & 63) + ((r >> 6) & 3);
    op[(size_t)k * R + m] = t[tx][ty + i * 8];
  }
}

// ---------------- persistent ADMM kernel -----------------------------------------
// 512 threads = 8 waves, block = (batch b = bid&7, 8 cols j0). 2 blocks/CU.
// Phase 1: each wave: 256 w-rows x 8 cols (R=4/lane), K-chunk 128 -> tree 8>4>2>1.
// Phase 2: wave pairs (w, w+4): 256 g-rows x 8 cols, K split 2 -> pair-reduce.
// s,w in LDS (stride-12 rows); e in VGPRs of waves 0-3. Bitwise == round 3.
__global__ __launch_bounds__(512, 4) void k_persist2(
    const float* __restrict__ W1s, const float* __restrict__ Vs,
    const float* __restrict__ PVPg, const double* __restrict__ Pg,
    double* __restrict__ Eg)
{
  const int bid = blockIdx.x;
  const int b = bid & 7;
  const int j0 = (bid >> 3) << 3;
  const float* W1p = W1s + (size_t)b * 262144;   // swizzled [1024][256]
  const float* Vp  = Vs  + (size_t)b * 262144;   // swizzled [256][1024]
  const float* Pvp = PVPg + (size_t)b * 262144;  // [256][1024]
  const double* P  = Pg + (size_t)b * 1048576 + j0;
  double* E        = Eg + (size_t)b * 1048576 + j0;

  const int tid = threadIdx.x;
  const int w   = tid >> 6;   // wave 0..7
  const int l   = tid & 63;   // lane

  __shared__ __align__(16) float s_ld[1024 * 12];  // 48 KB, row stride 12
  __shared__ __align__(16) float w_ld[256 * 12];   // 12 KB, row stride 12
  float* RED = s_ld;  // overlay: 4 slots x (64 lanes x 36 floats)

  // zero s
  for (int i = tid; i < 1024 * 12; i += 512) s_ld[i] = 0.0f;

  // e state: wave W<4, lane l owns rows 256*W + 64*t + l (t=0..3), cols 0..7
  double e[4][8];
#pragma unroll
  for (int t = 0; t < 4; ++t)
#pragma unroll
    for (int c = 0; c < 8; ++c) e[t][c] = 0.0;

  const double cg = 2.0 / 1024.0;
  float* slot = RED + (w & 3) * 2304 + l * 36;   // my reduction slot
  __syncthreads();

  for (int it = 0; it < 50; ++it) {
    // ================= phase 1: partial w = W1[:,chunk] @ s[chunk,:] ==========
    float acc[4][8];
#pragma unroll
    for (int t = 0; t < 4; ++t)
#pragma unroll
      for (int c = 0; c < 8; ++c) acc[t][c] = 0.0f;
    {
      const int k0 = w * 128;
      const float* w1ptr = W1p + (size_t)k0 * 256 + 4 * l;
#pragma unroll 4
      for (int k = 0; k < 128; ++k) {
        const float4* srow = reinterpret_cast<const float4*>(&s_ld[(k0 + k) * 12]);
        float4 s0 = srow[0], s1 = srow[1];
        float4 a = *reinterpret_cast<const float4*>(w1ptr + (size_t)k * 256);
        float av[4] = {a.x, a.y, a.z, a.w};
        float sv[8] = {s0.x, s0.y, s0.z, s0.w, s1.x, s1.y, s1.z, s1.w};
#pragma unroll
        for (int t = 0; t < 4; ++t)
#pragma unroll
          for (int c = 0; c < 8; ++c) acc[t][c] = fmaf(av[t], sv[c], acc[t][c]);
      }
    }
    __syncthreads();                       // all p1 sweeps done; s region free

    // reduction tree: ((c0+c4)+(c2+c6)) + ((c1+c5)+(c3+c7)), per chunk-index
    if (w >= 4) {
#pragma unroll
      for (int t = 0; t < 4; ++t)
#pragma unroll
        for (int q = 0; q < 2; ++q) {
          float4 v; v.x = acc[t][q*4]; v.y = acc[t][q*4+1]; v.z = acc[t][q*4+2]; v.w = acc[t][q*4+3];
          *reinterpret_cast<float4*>(slot + t * 8 + q * 4) = v;
        }
    }
    __syncthreads();
    if (w < 4) {
#pragma unroll
      for (int t = 0; t < 4; ++t)
#pragma unroll
        for (int q = 0; q < 2; ++q) {
          float4 v = *reinterpret_cast<const float4*>(slot + t * 8 + q * 4);
          acc[t][q*4] += v.x; acc[t][q*4+1] += v.y; acc[t][q*4+2] += v.z; acc[t][q*4+3] += v.w;
        }
    }
    __syncthreads();
    if (w == 2 || w == 3) {
      float* s2p = RED + (w - 2) * 2304 + l * 36;
#pragma unroll
      for (int t = 0; t < 4; ++t)
#pragma unroll
        for (int q = 0; q < 2; ++q) {
          float4 v; v.x = acc[t][q*4]; v.y = acc[t][q*4+1]; v.z = acc[t][q*4+2]; v.w = acc[t][q*4+3];
          *reinterpret_cast<float4*>(s2p + t * 8 + q * 4) = v;
        }
    }
    __syncthreads();
    if (w < 2) {
#pragma unroll
      for (int t = 0; t < 4; ++t)
#pragma unroll
        for (int q = 0; q < 2; ++q) {
          float4 v = *reinterpret_cast<const float4*>(slot + t * 8 + q * 4);
          acc[t][q*4] += v.x; acc[t][q*4+1] += v.y; acc[t][q*4+2] += v.z; acc[t][q*4+3] += v.w;
        }
    }
    __syncthreads();
    if (w == 1) {
      float* s0p = RED + l * 36;
#pragma unroll
      for (int t = 0; t < 4; ++t)
#pragma unroll
        for (int q = 0; q < 2; ++q) {
          float4 v; v.x = acc[t][q*4]; v.y = acc[t][q*4+1]; v.z = acc[t][q*4+2]; v.w = acc[t][q*4+3];
          *reinterpret_cast<float4*>(s0p + t * 8 + q * 4) = v;
        }
    }
    __syncthreads();
    if (w == 0) {
#pragma unroll
      for (int t = 0; t < 4; ++t) {
        const int row = l + 64 * t;
        const float* pvrow = Pvp + (size_t)row * 1024 + j0;
        float* wrow = &w_ld[row * 12];
#pragma unroll
        for (int q = 0; q < 2; ++q) {
          float4 v = *reinterpret_cast<const float4*>(slot + t * 8 + q * 4);
          float4 pv = *reinterpret_cast<const float4*>(pvrow + q * 4);
          float4 o;
          o.x = acc[t][q*4]   + v.x - pv.x;
          o.y = acc[t][q*4+1] + v.y - pv.y;
          o.z = acc[t][q*4+2] + v.z - pv.z;
          o.w = acc[t][q*4+3] + v.w - pv.w;
          *reinterpret_cast<float4*>(wrow + q * 4) = o;
        }
      }
    }
    __syncthreads();                       // w_ld ready

    // ================= phase 2: g = V @ w, rows 256*(w&3).., K split 2 ========
    float g[4][8];
#pragma unroll
    for (int t = 0; t < 4; ++t)
#pragma unroll
      for (int c = 0; c < 8; ++c) g[t][c] = 0.0f;
    {
      const int G = w & 3;
      const int kb = (w >> 2) * 128;
      const float* vptr = Vp + (size_t)kb * 1024 + 256 * G + 4 * l;
#pragma unroll 4
      for (int k = 0; k < 128; ++k) {
        const float4* wrow = reinterpret_cast<const float4*>(&w_ld[(kb + k) * 12]);
        float4 q0 = wrow[0], q1 = wrow[1];
        float4 a = *reinterpret_cast<const float4*>(vptr + (size_t)k * 1024);
        float av[4] = {a.x, a.y, a.z, a.w};
        float wv[8] = {q0.x, q0.y, q0.z, q0.w, q1.x, q1.y, q1.z, q1.w};
#pragma unroll
        for (int t = 0; t < 4; ++t)
#pragma unroll
          for (int c = 0; c < 8; ++c) g[t][c] = fmaf(av[t], wv[c], g[t][c]);
      }
    }
    if (w >= 4) {
#pragma unroll
      for (int t = 0; t < 4; ++t)
#pragma unroll
        for (int q = 0; q < 2; ++q) {
          float4 v; v.x = g[t][q*4]; v.y = g[t][q*4+1]; v.z = g[t][q*4+2]; v.w = g[t][q*4+3];
          *reinterpret_cast<float4*>(slot + t * 8 + q * 4) = v;
        }
    }
    __syncthreads();
    if (w < 4) {
#pragma unroll
      for (int t = 0; t < 4; ++t)
#pragma unroll
        for (int q = 0; q < 2; ++q) {
          float4 v = *reinterpret_cast<const float4*>(slot + t * 8 + q * 4);
          g[t][q*4] += v.x; g[t][q*4+1] += v.y; g[t][q*4+2] += v.z; g[t][q*4+3] += v.w;
        }
    }
    __syncthreads();                       // RED reads done; s region writable

    // ================= elementwise (waves 0-3) ================================
    if (w < 4) {
#pragma unroll
      for (int t = 0; t < 4; ++t) {
        const int row = 256 * w + 64 * t + l;
        const double* prow = P + (size_t)row * 1024;
        double p_[8];
#pragma unroll
        for (int q = 0; q < 4; ++q) {
          double2 pv = *reinterpret_cast<const double2*>(prow + 2 * q);
          p_[2*q] = pv.x; p_[2*q+1] = pv.y;
        }
        float s_[8];
#pragma unroll
        for (int c = 0; c < 8; ++c) {
          double z = clip01(e[t][c]);
          double en = z - p_[c] - cg * (double)g[t][c];
          e[t][c] = en;
          s_[c] = (float)(2.0 * clip01(en) - en);
        }
        float* srow = &s_ld[row * 12];
#pragma unroll
        for (int q = 0; q < 2; ++q) {
          float4 v; v.x = s_[q*4]; v.y = s_[q*4+1]; v.z = s_[q*4+2]; v.w = s_[q*4+3];
          *reinterpret_cast<float4*>(srow + q * 4) = v;
        }
      }
    }
    __syncthreads();                       // s ready for next iter
  }

  // final E store (waves 0-3)
  if (w < 4) {
#pragma unroll
    for (int t = 0; t < 4; ++t) {
      const int row = 256 * w + 64 * t + l;
      double* erow = E + (size_t)row * 1024;
#pragma unroll
      for (int q = 0; q < 4; ++q) {
        double2 v; v.x = e[t][2*q]; v.y = e[t][2*q+1];
        *reinterpret_cast<double2*>(erow + 2 * q) = v;
      }
    }
  }
}

// ---------------- per-(b,n) count -> inverse scale ------------------------------
__global__ __launch_bounds__(256) void k_count(const double* __restrict__ Eg, float* __restrict__ inv)
{
  const int bz = blockIdx.y;
  const int j = blockIdx.x * 256 + threadIdx.x;
  const double* E = Eg + (size_t)bz * 1048576;
  int c = 0;
  for (int i = 0; i < 1024; ++i) c += (E[(size_t)i * 1024 + j] > 0.5) ? 1 : 0;
  inv[bz * 1024 + j] = (float)(1.0 / (((double)c) + 1e-10) / 1024.0);
}

// ---------------- output masked GEMM: out[j,dd] = inv[j] * sum_i mask(e) V[i,dd] --
__global__ __launch_bounds__(256) void k_out(
    const double* __restrict__ Eg, const float* __restrict__ Vg,
    const float* __restrict__ invg, float* __restrict__ Og)
{
  const double* E = Eg + (size_t)blockIdx.z * 1048576;
  const float* Vv = Vg + (size_t)blockIdx.z * 262144;
  const float* inv = invg + blockIdx.z * 1024;
  float* O = Og + (size_t)blockIdx.z * 262144;
  const int j0 = blockIdx.x * 64, d0 = blockIdx.y * 128;
  const int tid = threadIdx.x;
  __shared__ float As[32][68];
  __shared__ float Bs[32][132];
  const int tx = tid & 15, ty = tid >> 4;
  const int ka = tid >> 3, ja = (tid & 7) * 8;
  const int rb = tid >> 5, cb = (tid & 31) * 4;
  float acc[4][8] = {};
  for (int k0 = 0; k0 < 1024; k0 += 32) {
    {
      const double2* ep = reinterpret_cast<const double2*>(E + (size_t)(k0 + ka) * 1024 + j0 + ja);
      double2 e0 = ep[0], e1 = ep[1], e2 = ep[2], e3 = ep[3];
      As[ka][ja + 0] = (e0.x > 0.5) ? 1.0f : 0.0f;
      As[ka][ja + 1] = (e0.y > 0.5) ? 1.0f : 0.0f;
      As[ka][ja + 2] = (e1.x > 0.5) ? 1.0f : 0.0f;
      As[ka][ja + 3] = (e1.y > 0.5) ? 1.0f : 0.0f;
      As[ka][ja + 4] = (e2.x > 0.5) ? 1.0f : 0.0f;
      As[ka][ja + 5] = (e2.y > 0.5) ? 1.0f : 0.0f;
      As[ka][ja + 6] = (e3.x > 0.5) ? 1.0f : 0.0f;
      As[ka][ja + 7] = (e3.y > 0.5) ? 1.0f : 0.0f;
    }
#pragma unroll
    for (int p = 0; p < 4; ++p) {
      int krow = rb + p * 8;
      float4 bv = *reinterpret_cast<const float4*>(Vv + (size_t)(k0 + krow) * 256 + d0 + cb);
      *reinterpret_cast<float4*>(&Bs[krow][cb]) = bv;
    }
    __syncthreads();
#pragma unroll
    for (int kk = 0; kk < 32; ++kk) {
      float4 av = *reinterpret_cast<const float4*>(&As[kk][ty * 4]);
      float4 b0 = *reinterpret_cast<const float4*>(&Bs[kk][tx * 8]);
      float4 b1 = *reinterpret_cast<const float4*>(&Bs[kk][tx * 8 + 4]);
      float a_[4] = {av.x, av.y, av.z, av.w};
      float b_[8] = {b0.x, b0.y, b0.z, b0.w, b1.x, b1.y, b1.z, b1.w};
#pragma unroll
      for (int i = 0; i < 4; ++i)
#pragma unroll
        for (int j = 0; j < 8; ++j) acc[i][j] = fmaf(a_[i], b_[j], acc[i][j]);
    }
    __syncthreads();
  }
#pragma unroll
  for (int i = 0; i < 4; ++i) {
    int row = j0 + ty * 4 + i;
    float sc = inv[row];
    size_t base = (size_t)row * 256 + d0 + tx * 8;
    float4 o0 = {acc[i][0] * sc, acc[i][1] * sc, acc[i][2] * sc, acc[i][3] * sc};
    float4 o1 = {acc[i][4] * sc, acc[i][5] * sc, acc[i][6] * sc, acc[i][7] * sc};
    *reinterpret_cast<float4*>(O + base) = o0;
    *reinterpret_cast<float4*>(O + base + 4) = o1;
  }
}

extern "C" void kernel_launch(void* const* d_in, const int* in_sizes, int n_in,
                              void* d_out, int out_size, void* d_ws, size_t ws_size,
                              hipStream_t stream)
{
  const float* Q = (const float*)d_in[0];   // (8,1024,256)
  const float* V = (const float*)d_in[1];   // (8,1024,256)
  float* out = (float*)d_out;               // (8,1024,256)
  char* ws = (char*)d_ws;

  // workspace layout (bytes) — total ~193 MB
  const size_t OFF_E   = 0;                  // e final, f64 (8,1024,1024)
  const size_t OFF_P   = 67108864;           // P, f64 (8,1024,1024)
  const size_t SCR     = 134217728;          // scratch region
  const size_t OFF_G   = SCR;
  const size_t OFF_AD  = SCR + 4194304;
  const size_t OFF_X   = SCR + 8388608;
  const size_t OFF_Y   = SCR + 12582912;
  const size_t OFF_X2  = SCR + 16777216;     // final M
  const size_t OFF_PV64= SCR;                // f64 (8,256,1024) overlays G..Y
  const size_t OFF_W1Z = SCR;                // fp32 swizzled W1 (8MB) — after PV64 dead
  const size_t OFF_VZ  = SCR + 8388608;      // fp32 swizzled V (8MB)
  const size_t OFF_W1  = 176160768;          // fp32 W1 (8,256,1024)
  const size_t OFF_PVP = 184549376;          // fp32 Pvp (8,256,1024)
  const size_t OFF_INV = 192937984;          // fp32 (8,1024)

  double* E    = (double*)(ws + OFF_E);
  double* P    = (double*)(ws + OFF_P);
  double* G    = (double*)(ws + OFF_G);
  double* Ad   = (double*)(ws + OFF_AD);
  double* X    = (double*)(ws + OFF_X);
  double* Y    = (double*)(ws + OFF_Y);
  double* X2   = (double*)(ws + OFF_X2);
  double* PV64 = (double*)(ws + OFF_PV64);
  float*  W1Z  = (float*)(ws + OFF_W1Z);
  float*  VZ   = (float*)(ws + OFF_VZ);
  float*  W1   = (float*)(ws + OFF_W1);
  float*  PVP  = (float*)(ws + OFF_PVP);
  float*  INV  = (float*)(ws + OFF_INV);

  (void)in_sizes; (void)n_in; (void)out_size; (void)ws_size;

  // P = (-2/1024) * V @ Q^T + 0.1/1024     (f64, K=256)
  k_gemm_nt<float, double><<<dim3(16, 16, 8), 256, 0, stream>>>(
      V, Q, P, 1024, 1024, 256, 262144, 262144, 1048576, -2.0 / 1024.0, 0.1 / 1024.0);

  // G = (1/1024^2) V^T @ V   (f64, 256x256)
  k_gemm_tn<float><<<dim3(4, 4, 8), 256, 0, stream>>>(
      V, V, G, 256, 256, 1024, 262144, 262144, 65536, 1.0 / 1048576.0);

  // Ad = I + 2G, X0 = I - 2G
  k_adx0<<<dim3(2048), 256, 0, stream>>>(G, Ad, X);

  // Newton-Schulz x3: X <- X(2I - Ad X); final M in X2
  for (int it = 0; it < 3; ++it) {
    const double* Xc = (it % 2 == 0) ? X : X2;
    double* Xn = (it % 2 == 0) ? X2 : X;
    k_smallmm<false><<<dim3(4, 4, 8), 256, 0, stream>>>(
        Ad, Xc, (const double*)nullptr, (void*)Y, 256, 65536, 65536, 1.0, 0.0);
    k_smallmm<false><<<dim3(4, 4, 8), 256, 0, stream>>>(
        Xc, Y, Xc, (void*)Xn, 256, 65536, 65536, -1.0, 2.0);
  }

  // PV64 = (1/1024) V^T @ P   (f64, 256x1024)
  k_gemm_tn<double><<<dim3(4, 16, 8), 256, 0, stream>>>(
      V, P, PV64, 256, 1024, 1024, 262144, 1048576, 262144, 1.0 / 1024.0);

  // PVP = M @ PV64  (fp32 out)
  k_smallmm<true><<<dim3(4, 16, 8), 256, 0, stream>>>(
      X2, PV64, (const double*)nullptr, (void*)PVP, 1024, 262144, 262144, 1.0, 0.0);

  // W1 = (1/1024) M @ V^T  (fp32 out, 256x1024)
  k_gemm_nt<double, float><<<dim3(4, 16, 8), 256, 0, stream>>>(
      X2, V, W1, 256, 1024, 256, 65536, 262144, 262144, 1.0 / 1024.0, 0.0);

  // swizzled operand layouts (PV64/X2 dead now)
  k_swzT<<<dim3(8, 32, 8), 256, 0, stream>>>(W1, W1Z, 256, 1024);
  k_swzT<<<dim3(32, 8, 8), 256, 0, stream>>>(V, VZ, 1024, 256);

  // 50 ADMM iterations, persistent: 1024 blocks x 512 threads (2 blocks/CU)
  k_persist2<<<dim3(1024), 512, 0, stream>>>(W1Z, VZ, PVP, P, E);

  // epilogue
  k_count<<<dim3(4, 8), 256, 0, stream>>>(E, INV);
  k_out<<<dim3(16, 2, 8), 256, 0, stream>>>(E, V, INV, out);
}